// Round 8
// baseline (356.229 us; speedup 1.0000x reference)
//
#include <hip/hip_runtime.h>
#include <hip/hip_bf16.h>

typedef __attribute__((ext_vector_type(8))) short bf16x8;
typedef __attribute__((ext_vector_type(4))) short bf16x4;
typedef __attribute__((ext_vector_type(4))) float f32x4;
typedef __attribute__((ext_vector_type(16))) float f32x16;
typedef __attribute__((ext_vector_type(4))) unsigned u32x4;

__device__ inline short f2bf(float f) {
    unsigned u = __builtin_bit_cast(unsigned, f);
    u += 0x7FFF + ((u >> 16) & 1);   // round-to-nearest-even
    return (short)(u >> 16);
}

// ws layout (units: shorts/bf16):
//   0        : Q   [32][2048][64]
//   4194304  : K   [32][2048][64]
//   8388608  : V^T [32][64][2048]
//   12582912 : xq_bf16 [4096][1024]
//   16777216 : xk_bf16 [4096][1024]
//   20971520 : Wq_bf16 [1024][1024]; +1M: Wk; +2M: Wv
//   24117248 : mask bias f32[2][2048] (= 0 or -1e9), 16KB

// ---------------------------------------------------------------------------
// f32 -> bf16 convert (memory-bound) + mask-bias build (block 11264).
// ---------------------------------------------------------------------------
__global__ __launch_bounds__(256) void cvt_bf16(
    const float* __restrict__ xq, const float* __restrict__ xk,
    const float* __restrict__ Wq, const float* __restrict__ Wk,
    const float* __restrict__ Wv, const int* __restrict__ key_mask,
    short* __restrict__ ws)
{
    const int blk = blockIdx.x;
    if (blk >= 11264) {
        float* bias = (float*)(ws + 24117248u);
        const int i0 = threadIdx.x * 4;
#pragma unroll
        for (int p = 0; p < 4; ++p) {
            int idx = p * 1024 + i0;          // 0..4095 = mb*2048 + k
            int4 m = *(const int4*)&key_mask[idx];
            f32x4 o = { m.x ? 0.f : -1e9f, m.y ? 0.f : -1e9f,
                        m.z ? 0.f : -1e9f, m.w ? 0.f : -1e9f };
            *(f32x4*)&bias[idx] = o;
        }
        return;
    }
    int seg, local;
    if (blk < 4096)      { seg = 0; local = blk; }
    else if (blk < 8192) { seg = 1; local = blk - 4096; }
    else                 { seg = 2 + ((blk - 8192) >> 10); local = (blk - 8192) & 1023; }
    const float* src = (seg == 0) ? xq : (seg == 1) ? xk
                     : (seg == 2) ? Wq : (seg == 3) ? Wk : Wv;
    const size_t dstoff = (seg == 0) ? 12582912u : (seg == 1) ? 16777216u
                        : 20971520u + (size_t)(seg - 2) * 1048576u;
    const size_t idx = (size_t)local * 1024 + threadIdx.x * 4;
    float4 v = *(const float4*)&src[idx];
    bf16x4 o = { f2bf(v.x), f2bf(v.y), f2bf(v.z), f2bf(v.w) };
    *(bf16x4*)&ws[dstoff + idx] = o;
}

// ---------------------------------------------------------------------------
// Projection GEMM (bf16): out = x @ W^T + bias.
// z=0: Q -> [bh][t][64]   z=1: K -> [bh][t][64]   z=2: V -> [bh][64][t]
// R8: 2-wave blocks, wave tile 64x128 (375B LDS-read/MFMA vs 512), padded
// LDS rows (40 shorts = 80B: conflict-free b128 frag reads), reg-staged
// T14 pipeline (loads 2 iters early; raw s_barrier + lgkmcnt(0); vmcnt
// waits own loads only — never drained across barriers).
// ---------------------------------------------------------------------------
__global__ __launch_bounds__(128, 2) void proj_gemm(
    short* __restrict__ ws, const float* __restrict__ bq,
    const float* __restrict__ bk, const float* __restrict__ bv)
{
    const int z = blockIdx.z;
    const short* A  = ws + ((z == 0) ? 12582912u : 16777216u);
    const short* Bw = ws + 20971520u + (size_t)z * 1048576u;
    const float* bias = (z == 0) ? bq : (z == 1) ? bk : bv;
    short* out = ws + (size_t)z * 4194304u;

    const int m0 = blockIdx.x * 128;
    const int n0 = blockIdx.y * 128;
    const int tid  = threadIdx.x;       // 0..127
    const int lane = tid & 63;
    const int wid  = tid >> 6;          // 0..1
    const int l15 = lane & 15, lhi = lane >> 4;

    // 2 buffers x (A[128][40] + B[128][40]) shorts = 40960B; epilogue overlays
    __shared__ alignas(16) short SM[20480];

    const int srow = tid >> 2;              // 0..31
    const int scol = (tid & 3) * 8;         // 0..24
    const short* aS = A  + (size_t)(m0 + srow) * 1024 + scol;
    const short* bS = Bw + (size_t)(n0 + srow) * 1024 + scol;
    const int ldso = srow * 40 + scol;

    bf16x8 stA[4], stB[4];

#define LOADT(T) do {                                                          \
    _Pragma("unroll")                                                          \
    for (int i_ = 0; i_ < 4; ++i_) {                                           \
        stA[i_] = *(const bf16x8*)(aS + (T) * 32 + i_ * 32768);                \
        stB[i_] = *(const bf16x8*)(bS + (T) * 32 + i_ * 32768);                \
    } } while (0)

#define WRITES(BUF) do {                                                       \
    short* wp_ = SM + (BUF) * 10240;                                           \
    _Pragma("unroll")                                                          \
    for (int i_ = 0; i_ < 4; ++i_) {                                           \
        *(bf16x8*)(wp_ + ldso + i_ * 1280) = stA[i_];                          \
        *(bf16x8*)(wp_ + 5120 + ldso + i_ * 1280) = stB[i_];                   \
    } } while (0)

    f32x4 acc[4][8] = {};

    // prologue: tile0 -> LDS buf0; tile1 loads in flight
    LOADT(0);
    asm volatile("s_waitcnt vmcnt(0)" ::: "memory");
    WRITES(0);
    LOADT(1);
    asm volatile("s_waitcnt lgkmcnt(0)" ::: "memory");
    __builtin_amdgcn_s_barrier();
    __builtin_amdgcn_sched_barrier(0);

    for (int t = 0; t < 32; ++t) {
        const short* SA = SM + (t & 1) * 10240;
        const short* SB = SA + 5120;

        bf16x8 a[4], b[8];
#pragma unroll
        for (int i = 0; i < 4; ++i)
            a[i] = *(const bf16x8*)&SA[(wid * 64 + i * 16 + l15) * 40 + lhi * 8];
#pragma unroll
        for (int j = 0; j < 8; ++j)
            b[j] = *(const bf16x8*)&SB[(j * 16 + l15) * 40 + lhi * 8];

        // stage tile t+1 into buf^1 (its last readers barrier'd at end of t-1);
        // issue tile t+2 loads — they stay in flight across the barrier.
        if (t < 31) {
            asm volatile("s_waitcnt vmcnt(0)" ::: "memory");
            WRITES((t + 1) & 1);
            if (t < 30) LOADT(t + 2);
        }

        if (z == 2) {
#pragma unroll
            for (int i = 0; i < 4; ++i)
#pragma unroll
                for (int j = 0; j < 8; ++j)
                    acc[i][j] = __builtin_amdgcn_mfma_f32_16x16x32_bf16(
                        a[i], b[j], acc[i][j], 0, 0, 0);
        } else {
#pragma unroll
            for (int i = 0; i < 4; ++i)
#pragma unroll
                for (int j = 0; j < 8; ++j)
                    acc[i][j] = __builtin_amdgcn_mfma_f32_16x16x32_bf16(
                        b[j], a[i], acc[i][j], 0, 0, 0);
        }

        if (t < 31) {
            asm volatile("s_waitcnt lgkmcnt(0)" ::: "memory");
            __builtin_amdgcn_s_barrier();
            __builtin_amdgcn_sched_barrier(0);
        }
    }
#undef LOADT
#undef WRITES

    // ---- epilogue: bias + pack, transpose via LDS overlay, 16B stores ----
    __syncthreads();
    if (z == 2) {
        // mfma(a,b): col(l15)=n, row(lhi*4+r)=m -> m contiguous per lane
#pragma unroll
        for (int i = 0; i < 4; ++i) {
            int mm = wid * 64 + i * 16 + lhi * 4;
#pragma unroll
            for (int j = 0; j < 8; ++j) {
                int nn = j * 16 + l15;
                float bval = bias[n0 + nn];
                bf16x4 pk = { f2bf(acc[i][j][0] + bval), f2bf(acc[i][j][1] + bval),
                              f2bf(acc[i][j][2] + bval), f2bf(acc[i][j][3] + bval) };
                *(bf16x4*)&SM[nn * 136 + mm] = pk;
            }
        }
    } else {
        // mfma(b,a): col(l15)=m, row(lhi*4+r)=n -> n contiguous per lane
#pragma unroll
        for (int i = 0; i < 4; ++i) {
            int mm = wid * 64 + i * 16 + l15;
#pragma unroll
            for (int j = 0; j < 8; ++j) {
                int nnb = j * 16 + lhi * 4;
                float4 bw = *(const float4*)&bias[n0 + nnb];
                bf16x4 pk = { f2bf(acc[i][j][0] + bw.x), f2bf(acc[i][j][1] + bw.y),
                              f2bf(acc[i][j][2] + bw.z), f2bf(acc[i][j][3] + bw.w) };
                *(bf16x4*)&SM[mm * 136 + nnb] = pk;
            }
        }
    }
    __syncthreads();

    const int bb = m0 >> 11;
    const int mt = m0 & 2047;
#pragma unroll
    for (int p = 0; p < 16; ++p) {
        int id = p * 128 + tid;
        int rr = id >> 4;               // 0..127
        int g  = id & 15;
        bf16x8 v = *(const bf16x8*)&SM[rr * 136 + g * 8];
        if (z == 2) {
            int nn = n0 + rr, h = nn >> 6, d = nn & 63;
            *(bf16x8*)&out[(((size_t)(bb * 16 + h)) * 64 + d) * 2048 + mt + g * 8] = v;
        } else {
            int nn = n0 + g * 8, h = nn >> 6, d = nn & 63;
            *(bf16x8*)&out[(((size_t)(bb * 16 + h)) * 2048 + mt + rr) * 64 + d] = v;
        }
    }
}

// ---------------------------------------------------------------------------
// Flash attention, in-block split-K (unchanged, R6/R7-verified). 512 thr = 8
// waves: wave (qg, ks) handles q-rows [qb*128+qg*32,+32) x keys [ks*1024,+1024).
// ---------------------------------------------------------------------------
__device__ inline float pair_max(float v) { return fmaxf(v, __shfl_xor(v, 32)); }
__device__ inline float pair_sum(float v) { return v + __shfl_xor(v, 32); }

__global__ __launch_bounds__(512, 4) void attn_fwd(
    const short* __restrict__ Qb, const short* __restrict__ Kb,
    const short* __restrict__ Vtb, const int* __restrict__ key_mask,
    const float* __restrict__ biasArr, float* __restrict__ out)
{
    const int bh = blockIdx.x;        // bh fastest: same-bh blocks -> same XCD
    const int qb = blockIdx.y;
    const int b  = bh >> 4;
    const int h  = bh & 15;
    const int mb = bh & 1;            // (b*H + h) % B, B=2
    const int tid  = threadIdx.x;
    const int lane = tid & 63;
    const int wid  = tid >> 6;        // 0..7
    const int qg   = wid & 3;         // q-group
    const int ks   = wid >> 2;        // k-split half
    const int l31  = lane & 31;
    const int hi   = lane >> 5;

    const size_t base = (size_t)bh * 2048 * 64;
    const int q0 = qb * 128 + qg * 32;
    const int ko = ks * 1024;

    __shared__ alignas(16) char SMEM[65536];
    short* KVbase = (short*)SMEM + ks * 16384;
#define KVS(BUF) (KVbase + (BUF) * 8192)

    const int* km_row = key_mask + mb * 2048;
    const float* bias_row = biasArr + mb * 2048;

    bf16x8 qf[4];
#pragma unroll
    for (int kf = 0; kf < 4; ++kf)
        qf[kf] = *(const bf16x8*)&Qb[base + (size_t)(q0 + l31) * 64 + kf * 16 + hi * 8];

    const int lrow = lane >> 3;
    const int lcol = (lane & 7) ^ (lrow & 7);
    const short* srcK[2];
    const short* srcV[2];
#pragma unroll
    for (int i = 0; i < 2; ++i) {
        int r0 = qg * 16 + i * 8;
        srcK[i] = Kb  + base + (size_t)(ko + r0 + lrow) * 64 + lcol * 8;
        srcV[i] = Vtb + base + (size_t)(r0 + lrow) * 2048 + ko + lcol * 8;
    }

    f32x16 acc[2];
#pragma unroll
    for (int n = 0; n < 2; ++n)
#pragma unroll
        for (int r = 0; r < 16; ++r) acc[n][r] = 0.f;
    float mrun = -1e30f, lrun = 0.f;
    const float SC  = 0.18033688f;    // 0.125 * log2(e)
    const float DTH = 44.3614f;       // 8 / SC : defer-max threshold

#define STAGE(T, BUF)                                                          \
    {                                                                          \
        _Pragma("unroll")                                                      \
        for (int i = 0; i < 2; ++i) {                                          \
            int r0 = qg * 16 + i * 8;                                          \
            __builtin_amdgcn_global_load_lds(                                  \
                (const __attribute__((address_space(1))) unsigned int*)        \
                    (srcK[i] + (size_t)(T) * 4096),                            \
                (__attribute__((address_space(3))) unsigned int*)              \
                    &KVS(BUF)[r0 * 64],                                        \
                16, 0, 0);                                                     \
            __builtin_amdgcn_global_load_lds(                                  \
                (const __attribute__((address_space(1))) unsigned int*)        \
                    (srcV[i] + (size_t)(T) * 64),                              \
                (__attribute__((address_space(3))) unsigned int*)              \
                    &KVS(BUF)[4096 + r0 * 64],                                 \
                16, 0, 0);                                                     \
        }                                                                      \
    }

    STAGE(0, 0);

    for (int t = 0; t < 16; ++t) {
        const int buf = t & 1;
        const int k0 = ko + t * 64;
        __syncthreads();
        if (t < 15) STAGE(t + 1, buf ^ 1);

        const f32x4* bp = (const f32x4*)(bias_row + k0);
        f32x16 sacc[2];
#pragma unroll
        for (int s = 0; s < 2; ++s) {
#pragma unroll
            for (int g = 0; g < 4; ++g) {
                f32x4 bv = bp[s * 8 + g * 2 + hi];
#pragma unroll
                for (int c = 0; c < 4; ++c) sacc[s][g * 4 + c] = bv[c];
            }
        }
        __builtin_amdgcn_s_setprio(1);
#pragma unroll
        for (int s = 0; s < 2; ++s) {
#pragma unroll
            for (int kf = 0; kf < 4; ++kf) {
                int row = s * 32 + l31;
                int xg = ((2 * kf + hi) ^ (row & 7)) * 8;
                bf16x8 kfr = *(const bf16x8*)&KVS(buf)[row * 64 + xg];
                sacc[s] = __builtin_amdgcn_mfma_f32_32x32x16_bf16(
                    kfr, qf[kf], sacc[s], 0, 0, 0);
            }
        }
        __builtin_amdgcn_s_setprio(0);

        float tm[16];
#pragma unroll
        for (int i = 0; i < 16; ++i) tm[i] = fmaxf(sacc[0][i], sacc[1][i]);
#pragma unroll
        for (int st = 8; st >= 1; st >>= 1)
#pragma unroll
            for (int i = 0; i < st; ++i) tm[i] = fmaxf(tm[i], tm[i + st]);
        float mx = pair_max(tm[0]);

        if (!__all(mx <= mrun + DTH)) {
            float mnew = fmaxf(mrun, mx);
            float fac  = __builtin_amdgcn_exp2f((mrun - mnew) * SC);
            lrun *= fac;
#pragma unroll
            for (int n = 0; n < 2; ++n)
#pragma unroll
                for (int r = 0; r < 16; ++r) acc[n][r] *= fac;
            mrun = mnew;
        }
        const float msc = mrun * SC;

        float p[2][16];
#pragma unroll
        for (int s = 0; s < 2; ++s)
#pragma unroll
            for (int r = 0; r < 16; ++r)
                p[s][r] = __builtin_amdgcn_exp2f(sacc[s][r] * SC - msc);

        float tsum[16];
#pragma unroll
        for (int i = 0; i < 16; ++i) tsum[i] = p[0][i] + p[1][i];
#pragma unroll
        for (int st = 8; st >= 1; st >>= 1)
#pragma unroll
            for (int i = 0; i < st; ++i) tsum[i] += tsum[i + st];
        lrun += pair_sum(tsum[0]);

        unsigned pk2[2][4][2];
#pragma unroll
        for (int s = 0; s < 2; ++s)
#pragma unroll
            for (int g = 0; g < 4; ++g)
#pragma unroll
                for (int w = 0; w < 2; ++w) {
                    unsigned d;
                    asm("v_cvt_pk_bf16_f32 %0, %1, %2"
                        : "=v"(d)
                        : "v"(p[s][g * 4 + 2 * w]), "v"(p[s][g * 4 + 2 * w + 1]));
                    pk2[s][g][w] = d;
                }

        __builtin_amdgcn_s_setprio(1);
#pragma unroll
        for (int s = 0; s < 2; ++s)
#pragma unroll
            for (int kk = 0; kk < 2; ++kk) {
                unsigned w0 = pk2[s][2 * kk][0],     w1 = pk2[s][2 * kk][1];
                unsigned w2 = pk2[s][2 * kk + 1][0], w3 = pk2[s][2 * kk + 1][1];
                asm("v_permlane32_swap_b32 %0, %1" : "+v"(w0), "+v"(w2));
                asm("v_permlane32_swap_b32 %0, %1" : "+v"(w1), "+v"(w3));
                u32x4 fv = { w0, w1, w2, w3 };
                bf16x8 pf = __builtin_bit_cast(bf16x8, fv);
                int kq = s * 2 + kk;
#pragma unroll
                for (int n = 0; n < 2; ++n) {
                    int row = n * 32 + l31;
                    int xg = ((2 * kq + hi) ^ (row & 7)) * 8;
                    bf16x8 vf = *(const bf16x8*)&KVS(buf)[4096 + row * 64 + xg];
                    acc[n] = __builtin_amdgcn_mfma_f32_32x32x16_bf16(
                        vf, pf, acc[n], 0, 0, 0);
                }
            }
        __builtin_amdgcn_s_setprio(0);
    }
#undef STAGE
#undef KVS

    // ---- split-K merge + epilogue ----
    __syncthreads();                       // (A) all KV reads complete
    float* R = (float*)SMEM + qg * 2176;   // per-qg region: O[64][32] | m | l

    if (ks == 1) {
#pragma unroll
        for (int n = 0; n < 2; ++n)
#pragma unroll
            for (int r = 0; r < 16; ++r) {
                int d = n * 32 + (r & 3) + 8 * (r >> 2) + 4 * hi;
                R[d * 32 + l31] = acc[n][r];
            }
        if (hi == 0) { R[2048 + l31] = mrun; R[2080 + l31] = lrun; }
    }
    __syncthreads();                       // (B) partner data visible

    if (ks == 0) {
        float m1 = R[2048 + l31];
        float l1 = R[2080 + l31];
        float o1[2][16];
#pragma unroll
        for (int n = 0; n < 2; ++n)
#pragma unroll
            for (int r = 0; r < 16; ++r) {
                int d = n * 32 + (r & 3) + 8 * (r >> 2) + 4 * hi;
                o1[n][r] = R[d * 32 + l31];
            }
        float mm = fmaxf(mrun, m1);
        float f0 = __builtin_amdgcn_exp2f((mrun - mm) * SC);
        float f1 = __builtin_amdgcn_exp2f((m1 - mm) * SC);
        float lt = lrun * f0 + l1 * f1;
        float qn = (float)km_row[q0 + l31] / lt;

#pragma unroll
        for (int n = 0; n < 2; ++n)
#pragma unroll
            for (int r = 0; r < 16; ++r) {
                int d = n * 32 + (r & 3) + 8 * (r >> 2) + 4 * hi;
                R[l31 * 68 + d] = (acc[n][r] * f0 + o1[n][r] * f1) * qn;
            }
        const int l15 = lane & 15, lq = lane >> 4;
#pragma unroll
        for (int rep = 0; rep < 8; ++rep) {
            int qr = rep * 4 + lq;
            f32x4 v = *(const f32x4*)&R[qr * 68 + l15 * 4];
            *(f32x4*)&out[((size_t)b * 2048 + q0 + qr) * 1024 + h * 64 + l15 * 4] = v;
        }
    }
}

extern "C" void kernel_launch(void* const* d_in, const int* in_sizes, int n_in,
                              void* d_out, int out_size, void* d_ws, size_t ws_size,
                              hipStream_t stream) {
    const float* queries = (const float*)d_in[0];
    const float* keys    = (const float*)d_in[1];
    const int*   key_mask= (const int*)d_in[2];
    const float* Wq = (const float*)d_in[3];
    const float* bq = (const float*)d_in[4];
    const float* Wk = (const float*)d_in[5];
    const float* bk = (const float*)d_in[6];
    const float* Wv = (const float*)d_in[7];
    const float* bv = (const float*)d_in[8];
    float* out = (float*)d_out;

    short* ws = (short*)d_ws;
    const float* biasArr = (const float*)(ws + 24117248u);

    cvt_bf16<<<11265, 256, 0, stream>>>(queries, keys, Wq, Wk, Wv, key_mask, ws);

    proj_gemm<<<dim3(32, 8, 3), 128, 0, stream>>>(ws, bq, bk, bv);

    attn_fwd<<<dim3(32, 16), 512, 0, stream>>>(
        ws, ws + 4194304, ws + 2 * 4194304, key_mask, biasArr, out);
}

// Round 9
// 119.432 us; speedup vs baseline: 2.9827x; 2.9827x over previous
//
#include <hip/hip_runtime.h>
#include <hip/hip_bf16.h>

typedef __attribute__((ext_vector_type(8))) short bf16x8;
typedef __attribute__((ext_vector_type(4))) short bf16x4;
typedef __attribute__((ext_vector_type(4))) float f32x4;
typedef __attribute__((ext_vector_type(16))) float f32x16;
typedef __attribute__((ext_vector_type(4))) unsigned u32x4;

__device__ inline short f2bf(float f) {
    unsigned u = __builtin_bit_cast(unsigned, f);
    u += 0x7FFF + ((u >> 16) & 1);   // round-to-nearest-even
    return (short)(u >> 16);
}

// ws layout (units: shorts/bf16):
//   0        : Q   [32][2048][64]
//   4194304  : K   [32][2048][64]
//   8388608  : V^T [32][64][2048]
//   12582912 : xq_bf16 [4096][1024]
//   16777216 : xk_bf16 [4096][1024]
//   20971520 : Wq_bf16 [1024][1024]; +1M: Wk; +2M: Wv
//   24117248 : mask bias f32[2][2048] (= 0 or -1e9), 16KB

// ---------------------------------------------------------------------------
// f32 -> bf16 convert (memory-bound) + mask-bias build (block 11264).
// ---------------------------------------------------------------------------
__global__ __launch_bounds__(256) void cvt_bf16(
    const float* __restrict__ xq, const float* __restrict__ xk,
    const float* __restrict__ Wq, const float* __restrict__ Wk,
    const float* __restrict__ Wv, const int* __restrict__ key_mask,
    short* __restrict__ ws)
{
    const int blk = blockIdx.x;
    if (blk >= 11264) {
        float* bias = (float*)(ws + 24117248u);
        const int i0 = threadIdx.x * 4;
#pragma unroll
        for (int p = 0; p < 4; ++p) {
            int idx = p * 1024 + i0;          // 0..4095 = mb*2048 + k
            int4 m = *(const int4*)&key_mask[idx];
            f32x4 o = { m.x ? 0.f : -1e9f, m.y ? 0.f : -1e9f,
                        m.z ? 0.f : -1e9f, m.w ? 0.f : -1e9f };
            *(f32x4*)&bias[idx] = o;
        }
        return;
    }
    int seg, local;
    if (blk < 4096)      { seg = 0; local = blk; }
    else if (blk < 8192) { seg = 1; local = blk - 4096; }
    else                 { seg = 2 + ((blk - 8192) >> 10); local = (blk - 8192) & 1023; }
    const float* src = (seg == 0) ? xq : (seg == 1) ? xk
                     : (seg == 2) ? Wq : (seg == 3) ? Wk : Wv;
    const size_t dstoff = (seg == 0) ? 12582912u : (seg == 1) ? 16777216u
                        : 20971520u + (size_t)(seg - 2) * 1048576u;
    const size_t idx = (size_t)local * 1024 + threadIdx.x * 4;
    float4 v = *(const float4*)&src[idx];
    bf16x4 o = { f2bf(v.x), f2bf(v.y), f2bf(v.z), f2bf(v.w) };
    *(bf16x4*)&ws[dstoff + idx] = o;
}

// ---------------------------------------------------------------------------
// Projection GEMM (bf16): out = x @ W^T + bias.  R6 structure + T2 swizzle.
// z=0: Q -> [bh][t][64]   z=1: K -> [bh][t][64]   z=2: V -> [bh][64][t]
// Swizzle (rule 21, both-sides): LDS[row][g] = global[row][g ^ ((row>>1)&3)]
// via pre-swizzled global_load_lds SOURCE (linear dest); reads XOR the same.
// Staging source group = (lane&3)^((lane>>3)&3); read group = lhi^((l15>>1)&3).
// ---------------------------------------------------------------------------
__global__ __launch_bounds__(256) void proj_gemm(
    short* __restrict__ ws, const float* __restrict__ bq,
    const float* __restrict__ bk, const float* __restrict__ bv)
{
    const int z = blockIdx.z;
    const short* A  = ws + ((z == 0) ? 12582912u : 16777216u);
    const short* Bw = ws + 20971520u + (size_t)z * 1048576u;
    const float* bias = (z == 0) ? bq : (z == 1) ? bk : bv;
    short* out = ws + (size_t)z * 4194304u;

    const int m0 = blockIdx.x * 128;
    const int n0 = blockIdx.y * 128;
    const int tid  = threadIdx.x;
    const int lane = tid & 63;
    const int wid  = tid >> 6;
    const int wr = wid >> 1, wc = wid & 1;
    const int l15 = lane & 15, lhi = lane >> 4;

    __shared__ alignas(16) short SM[17408];

    const int srow = wid * 32 + (lane >> 2);
    // pre-swizzled source 16B-group: (lane&3) ^ ((lane>>3)&3)
    const int sgrp = (lane & 3) ^ ((lane >> 3) & 3);
    const short* aSrc = A  + (size_t)(m0 + srow) * 1024 + sgrp * 8;
    const short* bSrc = Bw + (size_t)(n0 + srow) * 1024 + sgrp * 8;

#define PSTAGE(T, BUF) do {                                                    \
    _Pragma("unroll")                                                          \
    for (int i_ = 0; i_ < 2; ++i_) {                                           \
        __builtin_amdgcn_global_load_lds(                                      \
            (const __attribute__((address_space(1))) unsigned*)                \
                (aSrc + (T) * 32 + i_ * 16384),                                \
            (__attribute__((address_space(3))) unsigned*)                      \
                &SM[(BUF) * 8192 + (wid * 32 + i_ * 16) * 32], 16, 0, 0);      \
        __builtin_amdgcn_global_load_lds(                                      \
            (const __attribute__((address_space(1))) unsigned*)                \
                (bSrc + (T) * 32 + i_ * 16384),                                \
            (__attribute__((address_space(3))) unsigned*)                      \
                &SM[(BUF) * 8192 + 4096 + (wid * 32 + i_ * 16) * 32], 16, 0, 0);\
    } } while (0)

    f32x4 acc[4][4] = {};

    // read-side swizzled 16B-group: lhi ^ ((l15>>1)&3)  (rows are C+l15, C%16==0)
    const int rgrp = (lhi ^ ((l15 >> 1) & 3)) * 8;

    PSTAGE(0, 0);
    for (int t = 0; t < 32; ++t) {
        const int buf = t & 1;
        __syncthreads();
        if (t < 31) PSTAGE(t + 1, buf ^ 1);

        const short* SA = &SM[buf * 8192];
        const short* SB = SA + 4096;
        bf16x8 a[4], b[4];
#pragma unroll
        for (int i = 0; i < 4; ++i)
            a[i] = *(const bf16x8*)&SA[(wr * 64 + i * 16 + l15) * 32 + rgrp];
#pragma unroll
        for (int j = 0; j < 4; ++j)
            b[j] = *(const bf16x8*)&SB[(wc * 64 + j * 16 + l15) * 32 + rgrp];

        if (z == 2) {
#pragma unroll
            for (int i = 0; i < 4; ++i)
#pragma unroll
                for (int j = 0; j < 4; ++j)
                    acc[i][j] = __builtin_amdgcn_mfma_f32_16x16x32_bf16(
                        a[i], b[j], acc[i][j], 0, 0, 0);
        } else {
#pragma unroll
            for (int i = 0; i < 4; ++i)
#pragma unroll
                for (int j = 0; j < 4; ++j)
                    acc[i][j] = __builtin_amdgcn_mfma_f32_16x16x32_bf16(
                        b[j], a[i], acc[i][j], 0, 0, 0);
        }
    }
#undef PSTAGE

    __syncthreads();
    if (z == 2) {
#pragma unroll
        for (int i = 0; i < 4; ++i) {
            int mm = wr * 64 + i * 16 + lhi * 4;
#pragma unroll
            for (int j = 0; j < 4; ++j) {
                int nn = wc * 64 + j * 16 + l15;
                float bval = bias[n0 + nn];
                bf16x4 pk = { f2bf(acc[i][j][0] + bval), f2bf(acc[i][j][1] + bval),
                              f2bf(acc[i][j][2] + bval), f2bf(acc[i][j][3] + bval) };
                *(bf16x4*)&SM[nn * 136 + mm] = pk;
            }
        }
    } else {
#pragma unroll
        for (int i = 0; i < 4; ++i) {
            int mm = wr * 64 + i * 16 + l15;
#pragma unroll
            for (int j = 0; j < 4; ++j) {
                int nnb = wc * 64 + j * 16 + lhi * 4;
                float4 bw = *(const float4*)&bias[n0 + nnb];
                bf16x4 pk = { f2bf(acc[i][j][0] + bw.x), f2bf(acc[i][j][1] + bw.y),
                              f2bf(acc[i][j][2] + bw.z), f2bf(acc[i][j][3] + bw.w) };
                *(bf16x4*)&SM[mm * 136 + nnb] = pk;
            }
        }
    }
    __syncthreads();

    const int bb = m0 >> 11;
    const int mt = m0 & 2047;
#pragma unroll
    for (int p = 0; p < 8; ++p) {
        int id = p * 256 + tid;
        int rr = id >> 4;
        int g  = id & 15;
        bf16x8 v = *(const bf16x8*)&SM[rr * 136 + g * 8];
        if (z == 2) {
            int nn = n0 + rr, h = nn >> 6, d = nn & 63;
            *(bf16x8*)&out[(((size_t)(bb * 16 + h)) * 64 + d) * 2048 + mt + g * 8] = v;
        } else {
            int nn = n0 + g * 8, h = nn >> 6, d = nn & 63;
            *(bf16x8*)&out[(((size_t)(bb * 16 + h)) * 2048 + mt + rr) * 64 + d] = v;
        }
    }
}

// ---------------------------------------------------------------------------
// Flash attention, in-block split-K (unchanged, R6/R7-verified). 512 thr = 8
// waves: wave (qg, ks) handles q-rows [qb*128+qg*32,+32) x keys [ks*1024,+1024).
// ---------------------------------------------------------------------------
__device__ inline float pair_max(float v) { return fmaxf(v, __shfl_xor(v, 32)); }
__device__ inline float pair_sum(float v) { return v + __shfl_xor(v, 32); }

__global__ __launch_bounds__(512, 4) void attn_fwd(
    const short* __restrict__ Qb, const short* __restrict__ Kb,
    const short* __restrict__ Vtb, const int* __restrict__ key_mask,
    const float* __restrict__ biasArr, float* __restrict__ out)
{
    const int bh = blockIdx.x;        // bh fastest: same-bh blocks -> same XCD
    const int qb = blockIdx.y;
    const int b  = bh >> 4;
    const int h  = bh & 15;
    const int mb = bh & 1;            // (b*H + h) % B, B=2
    const int tid  = threadIdx.x;
    const int lane = tid & 63;
    const int wid  = tid >> 6;        // 0..7
    const int qg   = wid & 3;         // q-group
    const int ks   = wid >> 2;        // k-split half
    const int l31  = lane & 31;
    const int hi   = lane >> 5;

    const size_t base = (size_t)bh * 2048 * 64;
    const int q0 = qb * 128 + qg * 32;
    const int ko = ks * 1024;

    __shared__ alignas(16) char SMEM[65536];
    short* KVbase = (short*)SMEM + ks * 16384;
#define KVS(BUF) (KVbase + (BUF) * 8192)

    const int* km_row = key_mask + mb * 2048;
    const float* bias_row = biasArr + mb * 2048;

    bf16x8 qf[4];
#pragma unroll
    for (int kf = 0; kf < 4; ++kf)
        qf[kf] = *(const bf16x8*)&Qb[base + (size_t)(q0 + l31) * 64 + kf * 16 + hi * 8];

    const int lrow = lane >> 3;
    const int lcol = (lane & 7) ^ (lrow & 7);
    const short* srcK[2];
    const short* srcV[2];
#pragma unroll
    for (int i = 0; i < 2; ++i) {
        int r0 = qg * 16 + i * 8;
        srcK[i] = Kb  + base + (size_t)(ko + r0 + lrow) * 64 + lcol * 8;
        srcV[i] = Vtb + base + (size_t)(r0 + lrow) * 2048 + ko + lcol * 8;
    }

    f32x16 acc[2];
#pragma unroll
    for (int n = 0; n < 2; ++n)
#pragma unroll
        for (int r = 0; r < 16; ++r) acc[n][r] = 0.f;
    float mrun = -1e30f, lrun = 0.f;
    const float SC  = 0.18033688f;    // 0.125 * log2(e)
    const float DTH = 44.3614f;       // 8 / SC : defer-max threshold

#define STAGE(T, BUF)                                                          \
    {                                                                          \
        _Pragma("unroll")                                                      \
        for (int i = 0; i < 2; ++i) {                                          \
            int r0 = qg * 16 + i * 8;                                          \
            __builtin_amdgcn_global_load_lds(                                  \
                (const __attribute__((address_space(1))) unsigned int*)        \
                    (srcK[i] + (size_t)(T) * 4096),                            \
                (__attribute__((address_space(3))) unsigned int*)              \
                    &KVS(BUF)[r0 * 64],                                        \
                16, 0, 0);                                                     \
            __builtin_amdgcn_global_load_lds(                                  \
                (const __attribute__((address_space(1))) unsigned int*)        \
                    (srcV[i] + (size_t)(T) * 64),                              \
                (__attribute__((address_space(3))) unsigned int*)              \
                    &KVS(BUF)[4096 + r0 * 64],                                 \
                16, 0, 0);                                                     \
        }                                                                      \
    }

    STAGE(0, 0);

    for (int t = 0; t < 16; ++t) {
        const int buf = t & 1;
        const int k0 = ko + t * 64;
        __syncthreads();
        if (t < 15) STAGE(t + 1, buf ^ 1);

        const f32x4* bp = (const f32x4*)(bias_row + k0);
        f32x16 sacc[2];
#pragma unroll
        for (int s = 0; s < 2; ++s) {
#pragma unroll
            for (int g = 0; g < 4; ++g) {
                f32x4 bv = bp[s * 8 + g * 2 + hi];
#pragma unroll
                for (int c = 0; c < 4; ++c) sacc[s][g * 4 + c] = bv[c];
            }
        }
        __builtin_amdgcn_s_setprio(1);
#pragma unroll
        for (int s = 0; s < 2; ++s) {
#pragma unroll
            for (int kf = 0; kf < 4; ++kf) {
                int row = s * 32 + l31;
                int xg = ((2 * kf + hi) ^ (row & 7)) * 8;
                bf16x8 kfr = *(const bf16x8*)&KVS(buf)[row * 64 + xg];
                sacc[s] = __builtin_amdgcn_mfma_f32_32x32x16_bf16(
                    kfr, qf[kf], sacc[s], 0, 0, 0);
            }
        }
        __builtin_amdgcn_s_setprio(0);

        float tm[16];
#pragma unroll
        for (int i = 0; i < 16; ++i) tm[i] = fmaxf(sacc[0][i], sacc[1][i]);
#pragma unroll
        for (int st = 8; st >= 1; st >>= 1)
#pragma unroll
            for (int i = 0; i < st; ++i) tm[i] = fmaxf(tm[i], tm[i + st]);
        float mx = pair_max(tm[0]);

        if (!__all(mx <= mrun + DTH)) {
            float mnew = fmaxf(mrun, mx);
            float fac  = __builtin_amdgcn_exp2f((mrun - mnew) * SC);
            lrun *= fac;
#pragma unroll
            for (int n = 0; n < 2; ++n)
#pragma unroll
                for (int r = 0; r < 16; ++r) acc[n][r] *= fac;
            mrun = mnew;
        }
        const float msc = mrun * SC;

        float p[2][16];
#pragma unroll
        for (int s = 0; s < 2; ++s)
#pragma unroll
            for (int r = 0; r < 16; ++r)
                p[s][r] = __builtin_amdgcn_exp2f(sacc[s][r] * SC - msc);

        float tsum[16];
#pragma unroll
        for (int i = 0; i < 16; ++i) tsum[i] = p[0][i] + p[1][i];
#pragma unroll
        for (int st = 8; st >= 1; st >>= 1)
#pragma unroll
            for (int i = 0; i < st; ++i) tsum[i] += tsum[i + st];
        lrun += pair_sum(tsum[0]);

        unsigned pk2[2][4][2];
#pragma unroll
        for (int s = 0; s < 2; ++s)
#pragma unroll
            for (int g = 0; g < 4; ++g)
#pragma unroll
                for (int w = 0; w < 2; ++w) {
                    unsigned d;
                    asm("v_cvt_pk_bf16_f32 %0, %1, %2"
                        : "=v"(d)
                        : "v"(p[s][g * 4 + 2 * w]), "v"(p[s][g * 4 + 2 * w + 1]));
                    pk2[s][g][w] = d;
                }

        __builtin_amdgcn_s_setprio(1);
#pragma unroll
        for (int s = 0; s < 2; ++s)
#pragma unroll
            for (int kk = 0; kk < 2; ++kk) {
                unsigned w0 = pk2[s][2 * kk][0],     w1 = pk2[s][2 * kk][1];
                unsigned w2 = pk2[s][2 * kk + 1][0], w3 = pk2[s][2 * kk + 1][1];
                asm("v_permlane32_swap_b32 %0, %1" : "+v"(w0), "+v"(w2));
                asm("v_permlane32_swap_b32 %0, %1" : "+v"(w1), "+v"(w3));
                u32x4 fv = { w0, w1, w2, w3 };
                bf16x8 pf = __builtin_bit_cast(bf16x8, fv);
                int kq = s * 2 + kk;
#pragma unroll
                for (int n = 0; n < 2; ++n) {
                    int row = n * 32 + l31;
                    int xg = ((2 * kq + hi) ^ (row & 7)) * 8;
                    bf16x8 vf = *(const bf16x8*)&KVS(buf)[4096 + row * 64 + xg];
                    acc[n] = __builtin_amdgcn_mfma_f32_32x32x16_bf16(
                        vf, pf, acc[n], 0, 0, 0);
                }
            }
        __builtin_amdgcn_s_setprio(0);
    }
#undef STAGE
#undef KVS

    // ---- split-K merge + epilogue ----
    __syncthreads();                       // (A) all KV reads complete
    float* R = (float*)SMEM + qg * 2176;   // per-qg region: O[64][32] | m | l

    if (ks == 1) {
#pragma unroll
        for (int n = 0; n < 2; ++n)
#pragma unroll
            for (int r = 0; r < 16; ++r) {
                int d = n * 32 + (r & 3) + 8 * (r >> 2) + 4 * hi;
                R[d * 32 + l31] = acc[n][r];
            }
        if (hi == 0) { R[2048 + l31] = mrun; R[2080 + l31] = lrun; }
    }
    __syncthreads();                       // (B) partner data visible

    if (ks == 0) {
        float m1 = R[2048 + l31];
        float l1 = R[2080 + l31];
        float o1[2][16];
#pragma unroll
        for (int n = 0; n < 2; ++n)
#pragma unroll
            for (int r = 0; r < 16; ++r) {
                int d = n * 32 + (r & 3) + 8 * (r >> 2) + 4 * hi;
                o1[n][r] = R[d * 32 + l31];
            }
        float mm = fmaxf(mrun, m1);
        float f0 = __builtin_amdgcn_exp2f((mrun - mm) * SC);
        float f1 = __builtin_amdgcn_exp2f((m1 - mm) * SC);
        float lt = lrun * f0 + l1 * f1;
        float qn = (float)km_row[q0 + l31] / lt;

#pragma unroll
        for (int n = 0; n < 2; ++n)
#pragma unroll
            for (int r = 0; r < 16; ++r) {
                int d = n * 32 + (r & 3) + 8 * (r >> 2) + 4 * hi;
                R[l31 * 68 + d] = (acc[n][r] * f0 + o1[n][r] * f1) * qn;
            }
        const int l15 = lane & 15, lq = lane >> 4;
#pragma unroll
        for (int rep = 0; rep < 8; ++rep) {
            int qr = rep * 4 + lq;
            f32x4 v = *(const f32x4*)&R[qr * 68 + l15 * 4];
            *(f32x4*)&out[((size_t)b * 2048 + q0 + qr) * 1024 + h * 64 + l15 * 4] = v;
        }
    }
}

extern "C" void kernel_launch(void* const* d_in, const int* in_sizes, int n_in,
                              void* d_out, int out_size, void* d_ws, size_t ws_size,
                              hipStream_t stream) {
    const float* queries = (const float*)d_in[0];
    const float* keys    = (const float*)d_in[1];
    const int*   key_mask= (const int*)d_in[2];
    const float* Wq = (const float*)d_in[3];
    const float* bq = (const float*)d_in[4];
    const float* Wk = (const float*)d_in[5];
    const float* bk = (const float*)d_in[6];
    const float* Wv = (const float*)d_in[7];
    const float* bv = (const float*)d_in[8];
    float* out = (float*)d_out;

    short* ws = (short*)d_ws;
    const float* biasArr = (const float*)(ws + 24117248u);

    cvt_bf16<<<11265, 256, 0, stream>>>(queries, keys, Wq, Wk, Wv, key_mask, ws);

    proj_gemm<<<dim3(32, 8, 3), 256, 0, stream>>>(ws, bq, bk, bv);

    attn_fwd<<<dim3(32, 16), 512, 0, stream>>>(
        ws, ws + 4194304, ws + 2 * 4194304, key_mask, biasArr, out);
}